// Round 12
// baseline (505.463 us; speedup 1.0000x reference)
//
#include <hip/hip_runtime.h>
#include <hip/hip_bf16.h>

// AttentionLayer: out = softmax(32 * (xWq^T)(yWk^T)^T + causal) @ (zWv^T)
// N=8, S=T=2048, D=1024. All f32 in/out.
//
// R12: 256x256/BK32/8-wave gemm256 core (128KB dbuf LDS, counted-vmcnt
// depth-2) for z-proj, vT-proj, M' — grids exactly 256 blocks = single
// round, 2x MFMA per barrier, half the staging bytes/FLOP of the 128^2
// structure (which measured at its documented ~884 TF ceiling, R4-R10).
// qk stays 128^2 (256^2 tri grid = 288 blocks = 1.125-round tail kills
// the gain). Scores still = x(Wk^T Wq)y^T fold (R11).

typedef __attribute__((ext_vector_type(4))) float f32x4;
typedef __attribute__((ext_vector_type(8))) short bf16x8;
typedef __attribute__((ext_vector_type(4))) short s16x4;

#define DEVI __device__ __forceinline__

DEVI unsigned short f2bf(float x) {
  union { float f; unsigned u; } v; v.f = x;
  unsigned r = v.u + 0x7FFFu + ((v.u >> 16) & 1u);
  return (unsigned short)(r >> 16);
}
DEVI float bf2f(unsigned short b) {
  union { float f; unsigned u; } v; v.u = ((unsigned)b) << 16;
  return v.f;
}

DEVI void gload16(const void* g, void* l) {
#if __has_builtin(__builtin_amdgcn_global_load_lds)
  typedef __attribute__((address_space(1))) const unsigned int* gas_u32;
  typedef __attribute__((address_space(3))) unsigned int* las_u32;
  __builtin_amdgcn_global_load_lds(
      (gas_u32)(unsigned long long)g,
      (las_u32)(unsigned int)(unsigned long long)l, 16, 0, 0);
#else
  *(bf16x8*)l = *(const bf16x8*)g;
#endif
}

DEVI int xcd_swizzle(int bid, int nwg) {
  if (nwg & 7) return bid;
  int cpx = nwg >> 3;
  return (bid & 7) * cpx + (bid >> 3);
}

#define WAITBAR(N) asm volatile("s_waitcnt vmcnt(" #N ")\ns_barrier" ::: "memory")
#define BAR()      asm volatile("s_barrier" ::: "memory")

// 256-thread staging of a 128-row combined plane (row = [s0 64B | s1 64B]).
DEVI void stage_pair(const unsigned short* __restrict__ s0, long long rs0,
                     const unsigned short* __restrict__ s1, long long rs1,
                     short* lds, int tid) {
#pragma unroll
  for (int it = 0; it < 4; ++it) {
    int ii = it * 256 + tid;
    int r = ii >> 3;
    int c8 = (ii & 7) ^ (r & 7);
    const unsigned short* src = (c8 < 4)
        ? s0 + (long long)r * rs0 + (c8 & 3) * 8
        : s1 + (long long)r * rs1 + (c8 & 3) * 8;
    gload16(src, &lds[ii * 8]);
  }
}

constexpr int NB = 8, SS = 2048, TT = 2048, DD = 1024;
constexpr long long TILE_E = 16384;

// ---------------------------------------------------------------------------
// Elementwise split kernels.
// ---------------------------------------------------------------------------
__global__ __launch_bounds__(256) void split_hl_k(
    const float* __restrict__ in, unsigned short* __restrict__ hi,
    unsigned short* __restrict__ lo, long long n4)
{
  long long i = (long long)blockIdx.x * 256 + threadIdx.x;
  long long stride = (long long)gridDim.x * 256;
  for (; i < n4; i += stride) {
    f32x4 v = ((const f32x4*)in)[i];
    s16x4 h, l;
#pragma unroll
    for (int e = 0; e < 4; ++e) {
      unsigned short hh = f2bf(v[e]);
      h[e] = (short)hh;
      l[e] = (short)f2bf(v[e] - bf2f(hh));
    }
    ((s16x4*)hi)[i] = h;
    ((s16x4*)lo)[i] = l;
  }
}

__global__ __launch_bounds__(256) void split_h_k(
    const float* __restrict__ in, unsigned short* __restrict__ hi, long long n4)
{
  long long i = (long long)blockIdx.x * 256 + threadIdx.x;
  long long stride = (long long)gridDim.x * 256;
  for (; i < n4; i += stride) {
    f32x4 v = ((const f32x4*)in)[i];
    s16x4 h;
#pragma unroll
    for (int e = 0; e < 4; ++e) h[e] = (short)f2bf(v[e]);
    ((s16x4*)hi)[i] = h;
  }
}

// Transpose + split weights (tiny).
__global__ __launch_bounds__(256) void tsplit_k(
    const float* __restrict__ W, unsigned short* __restrict__ Th,
    unsigned short* __restrict__ Tl)
{
  __shared__ float t[64][68];
  int bi = blockIdx.x & 15, bj = blockIdx.x >> 4;
  int tid = threadIdx.x;
  int lr = tid >> 2, lc4 = tid & 3;
#pragma unroll
  for (int q = 0; q < 4; ++q) {
    int col = (lc4 + q * 4) * 4;
    f32x4 v = *(const f32x4*)(W + (long long)(bj * 64 + lr) * DD + bi * 64 + col);
    t[lr][col] = v[0]; t[lr][col + 1] = v[1];
    t[lr][col + 2] = v[2]; t[lr][col + 3] = v[3];
  }
  __syncthreads();
  int orow = tid >> 2, ch = tid & 3;
#pragma unroll
  for (int cc = 0; cc < 2; ++cc) {
    int c0 = (ch + cc * 4) * 8;
    bf16x8 h, l;
#pragma unroll
    for (int e = 0; e < 8; ++e) {
      float v = t[c0 + e][orow];
      unsigned short hh = f2bf(v);
      h[e] = (short)hh;
      l[e] = (short)f2bf(v - bf2f(hh));
    }
    long long o = (long long)(bi * 64 + orow) * DD + bj * 64 + c0;
    *(bf16x8*)(Th + o) = h;
    *(bf16x8*)(Tl + o) = l;
  }
}

// ---------------------------------------------------------------------------
// gemm256: C[M,Nn] = A[M,K] * B[Nn,K]^T on pre-split bf16 planes.
// 256x256 tile, BK=32, 8 waves (2x4), wave tile 128x64, depth-2 counted
// vmcnt. NMFMA=3: A,B hi/lo planes, 128KB LDS. NMFMA=1: hi only, 64KB.
// ---------------------------------------------------------------------------
template<int NMFMA, bool SPLIT_OUT>
__global__ __launch_bounds__(512, 2) void gemm256(
    const unsigned short* __restrict__ Ah_g, const unsigned short* __restrict__ Al_g,
    const unsigned short* __restrict__ Bh_g, const unsigned short* __restrict__ Bl_g,
    unsigned short* __restrict__ Chi, unsigned short* __restrict__ Clo,
    int Nn, int K,
    long long aStride, long long bStride, long long cStride,
    int tilesM, int tilesN)
{
  constexpr int HALF = (NMFMA == 3) ? 32768 : 16384;  // shorts per buffer
  __shared__ short lds[2 * HALF];

  int tid = threadIdx.x;
  int lane = tid & 63, wid = tid >> 6;
  int wr = wid >> 2, wc = wid & 3;        // 2x4 wave grid
  int l15 = lane & 15, lq = lane >> 4;

  int wg = xcd_swizzle(blockIdx.x, gridDim.x);
  int tilesPer = tilesM * tilesN;
  int b = wg / tilesPer;
  int rem = wg % tilesPer;
  int mt = rem / tilesN, nt = rem % tilesN;

  const unsigned short* Agh = Ah_g + (long long)b * aStride + (long long)mt * 256 * K;
  const unsigned short* Bgh = Bh_g + (long long)b * bStride + (long long)nt * 256 * K;
  const unsigned short* Agl = (NMFMA == 3) ? Al_g + (long long)b * aStride + (long long)mt * 256 * K : nullptr;
  const unsigned short* Bgl = (NMFMA == 3) ? Bl_g + (long long)b * bStride + (long long)nt * 256 * K : nullptr;

  f32x4 acc[8][4];
#pragma unroll
  for (int i = 0; i < 8; ++i)
#pragma unroll
    for (int j = 0; j < 4; ++j) acc[i][j] = (f32x4){0.f, 0.f, 0.f, 0.f};

  // stage one 256-row combined plane (row = [p0 64B | p1 64B]) with 512 thr
  auto stageP = [&](const unsigned short* p0, const unsigned short* p1,
                    int k0, short* dst) {
#pragma unroll
    for (int it = 0; it < 4; ++it) {
      int ii = it * 512 + tid;
      int r = ii >> 3;
      int c8 = (ii & 7) ^ (r & 7);
      const unsigned short* src = ((c8 < 4) ? p0 : p1) + (long long)r * K + k0 + (c8 & 3) * 8;
      gload16(src, &dst[ii * 8]);
    }
  };
  auto stage = [&](int t, int h) {
    int k0 = t * 32;
    if constexpr (NMFMA == 3) {
      stageP(Agh, Agl, k0, lds + h * HALF);           // A: [hi|lo]
      stageP(Bgh, Bgl, k0, lds + h * HALF + 16384);   // B: [hi|lo]
    } else {
      stageP(Agh, Bgh, k0, lds + h * HALF);           // [A|B]
    }
  };

  auto compute = [&](int h) {
    const short* A = lds + h * HALF;
    __builtin_amdgcn_s_setprio(1);
    if constexpr (NMFMA == 3) {
      const short* B = A + 16384;
      bf16x8 bh[4], bl[4];
#pragma unroll
      for (int j = 0; j < 4; ++j) {
        int rb = wc * 64 + j * 16 + l15;
        int sb = (rb & 7) << 4;
        bh[j] = *(const bf16x8*)(&B[((rb * 128 + lq * 16) ^ sb) >> 1]);
        bl[j] = *(const bf16x8*)(&B[((rb * 128 + 64 + lq * 16) ^ sb) >> 1]);
      }
#pragma unroll
      for (int i = 0; i < 8; ++i) {
        int ra = wr * 128 + i * 16 + l15;
        int sa = (ra & 7) << 4;
        bf16x8 ah = *(const bf16x8*)(&A[((ra * 128 + lq * 16) ^ sa) >> 1]);
        bf16x8 al = *(const bf16x8*)(&A[((ra * 128 + 64 + lq * 16) ^ sa) >> 1]);
#pragma unroll
        for (int j = 0; j < 4; ++j) {
          acc[i][j] = __builtin_amdgcn_mfma_f32_16x16x32_bf16(ah, bh[j], acc[i][j], 0, 0, 0);
          acc[i][j] = __builtin_amdgcn_mfma_f32_16x16x32_bf16(ah, bl[j], acc[i][j], 0, 0, 0);
          acc[i][j] = __builtin_amdgcn_mfma_f32_16x16x32_bf16(al, bh[j], acc[i][j], 0, 0, 0);
        }
      }
    } else {
      bf16x8 bfr[4];
#pragma unroll
      for (int j = 0; j < 4; ++j) {
        int rb = wc * 64 + j * 16 + l15;
        bfr[j] = *(const bf16x8*)(&A[((rb * 128 + 64 + lq * 16) ^ ((rb & 7) << 4)) >> 1]);
      }
#pragma unroll
      for (int i = 0; i < 8; ++i) {
        int ra = wr * 128 + i * 16 + l15;
        bf16x8 af = *(const bf16x8*)(&A[((ra * 128 + lq * 16) ^ ((ra & 7) << 4)) >> 1]);
#pragma unroll
        for (int j = 0; j < 4; ++j)
          acc[i][j] = __builtin_amdgcn_mfma_f32_16x16x32_bf16(af, bfr[j], acc[i][j], 0, 0, 0);
      }
    }
    __builtin_amdgcn_s_setprio(0);
  };

  int NT = K >> 5;
  stage(0, 0);
  stage(1, 1);
  for (int t = 0; t < NT; ++t) {
    if (t < NT - 1) {
      if constexpr (NMFMA == 3) WAITBAR(8); else WAITBAR(4);
    } else {
      WAITBAR(0);
    }
    compute(t & 1);
    BAR();
    if (t + 2 < NT) stage(t + 2, t & 1);
  }

  unsigned short* ch = Chi + (long long)b * cStride;
  unsigned short* cl = SPLIT_OUT ? (Clo + (long long)b * cStride) : nullptr;
#pragma unroll
  for (int i = 0; i < 8; ++i)
#pragma unroll
    for (int j = 0; j < 4; ++j)
#pragma unroll
      for (int e = 0; e < 4; ++e) {
        int row = mt * 256 + wr * 128 + i * 16 + lq * 4 + e;
        int col = nt * 256 + wc * 64 + j * 16 + l15;
        float vv = acc[i][j][e];
        unsigned short h = f2bf(vv);
        ch[(long long)row * Nn + col] = h;
        if constexpr (SPLIT_OUT) cl[(long long)row * Nn + col] = f2bf(vv - bf2f(h));
      }
}

// ---------------------------------------------------------------------------
// QK^T: bf16x3, 128x128 lower-triangular tiles, packed tile output.
// Counted-vmcnt depth-2, 64KB dbuf, 2 blocks/CU. (verified R10/R11)
// ---------------------------------------------------------------------------
__global__ __launch_bounds__(256, 2) void qk_bt(
    const unsigned short* __restrict__ qh, const unsigned short* __restrict__ ql,
    const unsigned short* __restrict__ kh, const unsigned short* __restrict__ kl,
    float* __restrict__ Sg)
{
  __shared__ short lds[2 * 16384];

  int tid = threadIdx.x;
  int lane = tid & 63, wid = tid >> 6;
  int wr = wid >> 1, wc = wid & 1;
  int l15 = lane & 15, lq = lane >> 4;

  int wg = xcd_swizzle(blockIdx.x, gridDim.x);
  int b = wg / 136;
  int idx = wg % 136;
  int st = (int)((sqrtf(8.f * (float)idx + 1.f) - 1.f) * 0.5f);
  while ((st + 1) * (st + 2) / 2 <= idx) ++st;
  while (st * (st + 1) / 2 > idx) --st;
  int tt = idx - st * (st + 1) / 2;

  const unsigned short* Agh = qh + (long long)b * SS * DD + (long long)st * 128 * DD;
  const unsigned short* Agl = ql + (long long)b * SS * DD + (long long)st * 128 * DD;
  const unsigned short* Bgh = kh + (long long)b * TT * DD + (long long)tt * 128 * DD;
  const unsigned short* Bgl = kl + (long long)b * TT * DD + (long long)tt * 128 * DD;

  f32x4 acc[4][4];
#pragma unroll
  for (int i = 0; i < 4; ++i)
#pragma unroll
    for (int j = 0; j < 4; ++j) acc[i][j] = (f32x4){0.f, 0.f, 0.f, 0.f};

  auto stage = [&](int t, int h) {
    int k0 = t * 32;
    stage_pair(Agh + k0, DD, Agl + k0, DD, lds + h * 16384, tid);
    stage_pair(Bgh + k0, DD, Bgl + k0, DD, lds + h * 16384 + 8192, tid);
  };
  auto compute = [&](int h) {
    __builtin_amdgcn_s_setprio(1);
    const short* U = lds + h * 16384;
    const short* V = U + 8192;
    bf16x8 afh[4], afl[4], bfh[4], bfl[4];
#pragma unroll
    for (int i = 0; i < 4; ++i) {
      int ra = wr * 64 + i * 16 + l15;
      int sa = (ra & 7) << 4;
      afh[i] = *(const bf16x8*)(&U[((ra * 128 + lq * 16) ^ sa) >> 1]);
      afl[i] = *(const bf16x8*)(&U[((ra * 128 + 64 + lq * 16) ^ sa) >> 1]);
      int rb = wc * 64 + i * 16 + l15;
      int sb = (rb & 7) << 4;
      bfh[i] = *(const bf16x8*)(&V[((rb * 128 + lq * 16) ^ sb) >> 1]);
      bfl[i] = *(const bf16x8*)(&V[((rb * 128 + 64 + lq * 16) ^ sb) >> 1]);
    }
#pragma unroll
    for (int i = 0; i < 4; ++i)
#pragma unroll
      for (int j = 0; j < 4; ++j) {
        acc[i][j] = __builtin_amdgcn_mfma_f32_16x16x32_bf16(afh[i], bfh[j], acc[i][j], 0, 0, 0);
        acc[i][j] = __builtin_amdgcn_mfma_f32_16x16x32_bf16(afh[i], bfl[j], acc[i][j], 0, 0, 0);
        acc[i][j] = __builtin_amdgcn_mfma_f32_16x16x32_bf16(afl[i], bfh[j], acc[i][j], 0, 0, 0);
      }
    __builtin_amdgcn_s_setprio(0);
  };

  stage(0, 0);
  stage(1, 1);
  for (int t = 0; t < 32; ++t) {
    if (t < 31) WAITBAR(8); else WAITBAR(0);
    compute(t & 1);
    BAR();
    if (t + 2 < 32) stage(t + 2, t & 1);
  }

  float* Sb = Sg + ((long long)b * 136 + idx) * TILE_E;
#pragma unroll
  for (int i = 0; i < 4; ++i)
#pragma unroll
    for (int j = 0; j < 4; ++j)
#pragma unroll
      for (int e = 0; e < 4; ++e) {
        int row = wr * 64 + i * 16 + lq * 4 + e;
        int col = wc * 64 + j * 16 + l15;
        Sb[(long long)row * 128 + col] = acc[i][j][e];
      }
}

// ---------------------------------------------------------------------------
// Row softmax over packed triangular tiles (causal, *32). P bf16 in place.
// ---------------------------------------------------------------------------
__global__ __launch_bounds__(256) void softmax_kernel(float* __restrict__ Sg)
{
  __shared__ float red[8];
  int blk = blockIdx.x;
  int b = blk >> 11, s = blk & 2047;
  int st = s >> 7, r = s & 127;
  long long tri = (long long)st * (st + 1) / 2;
  const float* tb = Sg + ((long long)b * 136 + tri) * TILE_E + (long long)r * 128;

  int tid = threadIdx.x;
  int lane = tid & 63, wid = tid >> 6;

  int c0 = tid * 8;
  int tt = c0 >> 7, cc = c0 & 127;
  bool live = (c0 <= s);
  f32x4 v0 = {0.f, 0.f, 0.f, 0.f}, v1 = {0.f, 0.f, 0.f, 0.f};
  if (live) {
    const float* seg = tb + (long long)tt * TILE_E + cc;
    v0 = *(const f32x4*)seg;
    v1 = *(const f32x4*)(seg + 4);
  }

  float m = -3.0e38f;
#pragma unroll
  for (int e = 0; e < 4; ++e) {
    if (c0 + e <= s) m = fmaxf(m, v0[e]);
    if (c0 + 4 + e <= s) m = fmaxf(m, v1[e]);
  }
#pragma unroll
  for (int o = 32; o > 0; o >>= 1) m = fmaxf(m, __shfl_xor(m, o));
  if (lane == 0) red[wid] = m;
  __syncthreads();
  m = fmaxf(fmaxf(red[0], red[1]), fmaxf(red[2], red[3]));

  const float C = 46.16624130844683f;  // 32 * log2(e)
  float p0[4], p1[4];
  float sum = 0.f;
#pragma unroll
  for (int e = 0; e < 4; ++e) {
    p0[e] = (c0 + e <= s) ? exp2f((v0[e] - m) * C) : 0.f;
    sum += p0[e];
    p1[e] = (c0 + 4 + e <= s) ? exp2f((v1[e] - m) * C) : 0.f;
    sum += p1[e];
  }
#pragma unroll
  for (int o = 32; o > 0; o >>= 1) sum += __shfl_xor(sum, o);
  if (lane == 0) red[4 + wid] = sum;
  __syncthreads();
  float inv = 1.f / (red[4] + red[5] + red[6] + red[7]);

  union { bf16x8 v; s16x4 h[2]; } w;
#pragma unroll
  for (int e = 0; e < 4; ++e) {
    w.h[0][e] = (short)f2bf(p0[e] * inv);
    w.h[1][e] = (short)f2bf(p1[e] * inv);
  }
  __syncthreads();
  if (c0 < (st + 1) * 128) {
    unsigned short* pw = (unsigned short*)Sg +
        (((long long)b * 136 + tri + tt) * TILE_E) * 2 + (long long)r * 256 + cc;
    *(bf16x8*)pw = w.v;
  }
}

// ---------------------------------------------------------------------------
// PV: O[s,d] = sum_t P[s,t]*vT[d,t]. Counted-vmcnt depth-2; longest first.
// ---------------------------------------------------------------------------
__global__ __launch_bounds__(256, 2) void pv_bt(
    const unsigned short* __restrict__ P, const unsigned short* __restrict__ vT,
    float* __restrict__ Out)
{
  __shared__ short lds[2 * 8192];

  int tid = threadIdx.x;
  int lane = tid & 63, wid = tid >> 6;
  int wr = wid >> 1, wc = wid & 1;
  int l15 = lane & 15, lq = lane >> 4;

  int wg = xcd_swizzle(blockIdx.x, gridDim.x);
  int b = wg >> 7;
  int rem = wg & 127;
  int st = 15 - (rem >> 3);
  int dt = rem & 7;

  const unsigned short* Ps = P + ((long long)b * 136 + (long long)st * (st + 1) / 2) * (TILE_E * 2);
  const unsigned short* Vb = vT + (long long)b * DD * TT + (long long)dt * 128 * TT;
  int NT = (st + 1) * 4;

  f32x4 acc[4][4];
#pragma unroll
  for (int i = 0; i < 4; ++i)
#pragma unroll
    for (int j = 0; j < 4; ++j) acc[i][j] = (f32x4){0.f, 0.f, 0.f, 0.f};

  auto stage = [&](int t, int h) {
    int t0 = t * 32;
    const unsigned short* s0 = Ps + (long long)(t0 >> 7) * (TILE_E * 2) + (t0 & 127);
    stage_pair(s0, 256, Vb + t0, TT, lds + h * 8192, tid);
  };
  auto compute = [&](int h) {
    __builtin_amdgcn_s_setprio(1);
    const short* W = lds + h * 8192;
    bf16x8 af[4], bfr[4];
#pragma unroll
    for (int i = 0; i < 4; ++i) {
      int ra = wr * 64 + i * 16 + l15;
      af[i] = *(const bf16x8*)(&W[((ra * 128 + lq * 16) ^ ((ra & 7) << 4)) >> 1]);
      int rb = wc * 64 + i * 16 + l15;
      bfr[i] = *(const bf16x8*)(&W[((rb * 128 + 64 + lq * 16) ^ ((rb & 7) << 4)) >> 1]);
    }
#pragma unroll
    for (int i = 0; i < 4; ++i)
#pragma unroll
      for (int j = 0; j < 4; ++j)
        acc[i][j] = __builtin_amdgcn_mfma_f32_16x16x32_bf16(af[i], bfr[j], acc[i][j], 0, 0, 0);
    __builtin_amdgcn_s_setprio(0);
  };

  stage(0, 0);
  stage(1, 1);
  for (int t = 0; t < NT; ++t) {
    if (t < NT - 1) WAITBAR(4); else WAITBAR(0);
    compute(t & 1);
    BAR();
    if (t + 2 < NT) stage(t + 2, t & 1);
  }

  float* Ob = Out + (long long)b * SS * DD;
#pragma unroll
  for (int i = 0; i < 4; ++i)
#pragma unroll
    for (int j = 0; j < 4; ++j)
#pragma unroll
      for (int e = 0; e < 4; ++e) {
        int row = st * 128 + wr * 64 + i * 16 + lq * 4 + e;
        int col = dt * 128 + wc * 64 + j * 16 + l15;
        Ob[(long long)row * DD + col] = acc[i][j][e];
      }
}

// ---------------------------------------------------------------------------
extern "C" void kernel_launch(void* const* d_in, const int* in_sizes, int n_in,
                              void* d_out, int out_size, void* d_ws, size_t ws_size,
                              hipStream_t stream) {
  (void)in_sizes; (void)n_in; (void)out_size;
  const float* key   = (const float*)d_in[0];
  const float* query = (const float*)d_in[1];
  const float* value = (const float*)d_in[2];
  const float* Wq    = (const float*)d_in[3];
  const float* Wk    = (const float*)d_in[4];
  const float* Wv    = (const float*)d_in[5];
  float* Out = (float*)d_out;

  const long long SD = (long long)SS * DD;
  const long long DT = (long long)DD * TT;
  const long long WN = (long long)DD * DD;

  const unsigned long long PLANE_B  = (unsigned long long)SD * 2;
  const unsigned long long WPLANE_B = (unsigned long long)WN * 2;
  const unsigned long long SCORE_B  = 136ull * TILE_E * 4;

  auto need = [&](int g) -> unsigned long long {
    return 3ull * WPLANE_B + (unsigned long long)g * (SCORE_B + 5ull * PLANE_B);
  };
  int G = 1;
  for (int g : {8, 4, 2, 1}) if (ws_size >= need(g)) { G = g; break; }

  char* ws = (char*)d_ws;
  size_t off = 0;
  auto alloc = [&](unsigned long long bytes) { char* p = ws + off; off += bytes; return p; };

  unsigned short* mph = (unsigned short*)alloc(WPLANE_B);
  unsigned short* mpl = (unsigned short*)alloc(WPLANE_B);
  unsigned short* wvh = (unsigned short*)alloc(WPLANE_B);
  char* slab = alloc((unsigned long long)G * SCORE_B);
  unsigned short* qh  = (unsigned short*)alloc((unsigned long long)G * PLANE_B);
  unsigned short* ql  = (unsigned short*)alloc((unsigned long long)G * PLANE_B);
  unsigned short* kh  = (unsigned short*)alloc((unsigned long long)G * PLANE_B);
  unsigned short* kl  = (unsigned short*)alloc((unsigned long long)G * PLANE_B);
  unsigned short* vT  = (unsigned short*)alloc((unsigned long long)G * PLANE_B);

  unsigned short* wqTh = (unsigned short*)slab;
  unsigned short* wqTl = (unsigned short*)(slab + WPLANE_B);
  unsigned short* wkTh = (unsigned short*)(slab + 2 * WPLANE_B);
  unsigned short* wkTl = (unsigned short*)(slab + 3 * WPLANE_B);

  unsigned short* iah = (unsigned short*)slab;
  unsigned short* ial = (unsigned short*)(slab + (unsigned long long)G * PLANE_B);
  float* Sg = (float*)slab;

  // M' = Wk^T Wq (hi+lo), tiny 1024^3
  tsplit_k<<<256, 256, 0, stream>>>(Wq, wqTh, wqTl);
  tsplit_k<<<256, 256, 0, stream>>>(Wk, wkTh, wkTl);
  split_h_k<<<512, 256, 0, stream>>>(Wv, wvh, WN / 4);
  gemm256<3, true><<<16, 512, 0, stream>>>(
      wkTh, wkTl, wqTh, wqTl, mph, mpl, DD, DD, 0, 0, 0, 4, 4);

  for (int b0 = 0; b0 < NB; b0 += G) {
    long long n4 = (long long)G * SD / 4;
    // z = x M'^T : 256^2 tiles, grid G*32 = 256 (single round)
    split_hl_k<<<2048, 256, 0, stream>>>(query + (long long)b0 * SD, iah, ial, n4);
    gemm256<3, true><<<G * 32, 512, 0, stream>>>(
        iah, ial, mph, mpl, qh, ql, DD, DD, SD, 0, SD, 8, 4);
    // key: exact hi/lo split (B operand of the score GEMM)
    split_hl_k<<<2048, 256, 0, stream>>>(key + (long long)b0 * SD, kh, kl, n4);
    // vT = Wv @ value^T : 256^2 tiles, grid G*32 = 256
    split_h_k<<<2048, 256, 0, stream>>>(value + (long long)b0 * SD, iah, n4);
    gemm256<1, false><<<G * 32, 512, 0, stream>>>(
        wvh, nullptr, iah, nullptr, vT, nullptr, TT, DD, 0, SD, DT, 4, 8);
    // scores = z key^T (triangular), softmax, PV
    qk_bt<<<G * 136, 256, 0, stream>>>(qh, ql, kh, kl, Sg);
    softmax_kernel<<<G * SS, 256, 0, stream>>>(Sg);
    pv_bt<<<G * 128, 256, 0, stream>>>(
        (const unsigned short*)Sg, vT, Out + (long long)b0 * SD);
  }
}

// Round 13
// 497.341 us; speedup vs baseline: 1.0163x; 1.0163x over previous
//
#include <hip/hip_runtime.h>
#include <hip/hip_bf16.h>

// AttentionLayer: out = softmax(32 * (xWq^T)(yWk^T)^T + causal) @ (zWv^T)
// N=8, S=T=2048, D=1024. All f32 in/out.
//
// R13: R11 base + 8-phase-style gemm256p8 for the z-projection only.
// R12 proved 256^2 at a 2-barrier schedule = no gain (matches guide's
// tile-space table); the lever is the phase-split interleave (T3): each
// BK=32 K-step computed in 4 barriered phases of {12 ds_read_b128 +
// 24 MFMA + setprio}, depth-2 counted vmcnt (R10's verified WAITBAR(8)
// skeleton), stage-issue after the final phase barrier. z-proj grid =
// exactly 256 blocks at 1 block/CU (128KB LDS). qk/pv/vT/M'/softmax =
// R11 verbatim.

typedef __attribute__((ext_vector_type(4))) float f32x4;
typedef __attribute__((ext_vector_type(8))) short bf16x8;
typedef __attribute__((ext_vector_type(4))) short s16x4;

#define DEVI __device__ __forceinline__

DEVI unsigned short f2bf(float x) {
  union { float f; unsigned u; } v; v.f = x;
  unsigned r = v.u + 0x7FFFu + ((v.u >> 16) & 1u);
  return (unsigned short)(r >> 16);
}
DEVI float bf2f(unsigned short b) {
  union { float f; unsigned u; } v; v.u = ((unsigned)b) << 16;
  return v.f;
}

DEVI void gload16(const void* g, void* l) {
#if __has_builtin(__builtin_amdgcn_global_load_lds)
  typedef __attribute__((address_space(1))) const unsigned int* gas_u32;
  typedef __attribute__((address_space(3))) unsigned int* las_u32;
  __builtin_amdgcn_global_load_lds(
      (gas_u32)(unsigned long long)g,
      (las_u32)(unsigned int)(unsigned long long)l, 16, 0, 0);
#else
  *(bf16x8*)l = *(const bf16x8*)g;
#endif
}

DEVI int xcd_swizzle(int bid, int nwg) {
  if (nwg & 7) return bid;
  int cpx = nwg >> 3;
  return (bid & 7) * cpx + (bid >> 3);
}

#define WAITBAR(N) asm volatile("s_waitcnt vmcnt(" #N ")\ns_barrier" ::: "memory")
#define BAR()      asm volatile("s_barrier" ::: "memory")

// 256-thread staging of a 128-row combined plane (row = [s0 64B | s1 64B]).
DEVI void stage_pair(const unsigned short* __restrict__ s0, long long rs0,
                     const unsigned short* __restrict__ s1, long long rs1,
                     short* lds, int tid) {
#pragma unroll
  for (int it = 0; it < 4; ++it) {
    int ii = it * 256 + tid;
    int r = ii >> 3;
    int c8 = (ii & 7) ^ (r & 7);
    const unsigned short* src = (c8 < 4)
        ? s0 + (long long)r * rs0 + (c8 & 3) * 8
        : s1 + (long long)r * rs1 + (c8 & 3) * 8;
    gload16(src, &lds[ii * 8]);
  }
}

constexpr int NB = 8, SS = 2048, TT = 2048, DD = 1024;
constexpr long long TILE_E = 16384;

// ---------------------------------------------------------------------------
// Elementwise split kernels.
// ---------------------------------------------------------------------------
__global__ __launch_bounds__(256) void split_hl_k(
    const float* __restrict__ in, unsigned short* __restrict__ hi,
    unsigned short* __restrict__ lo, long long n4)
{
  long long i = (long long)blockIdx.x * 256 + threadIdx.x;
  long long stride = (long long)gridDim.x * 256;
  for (; i < n4; i += stride) {
    f32x4 v = ((const f32x4*)in)[i];
    s16x4 h, l;
#pragma unroll
    for (int e = 0; e < 4; ++e) {
      unsigned short hh = f2bf(v[e]);
      h[e] = (short)hh;
      l[e] = (short)f2bf(v[e] - bf2f(hh));
    }
    ((s16x4*)hi)[i] = h;
    ((s16x4*)lo)[i] = l;
  }
}

__global__ __launch_bounds__(256) void split_h_k(
    const float* __restrict__ in, unsigned short* __restrict__ hi, long long n4)
{
  long long i = (long long)blockIdx.x * 256 + threadIdx.x;
  long long stride = (long long)gridDim.x * 256;
  for (; i < n4; i += stride) {
    f32x4 v = ((const f32x4*)in)[i];
    s16x4 h;
#pragma unroll
    for (int e = 0; e < 4; ++e) h[e] = (short)f2bf(v[e]);
    ((s16x4*)hi)[i] = h;
  }
}

// Transpose + split weights (tiny).
__global__ __launch_bounds__(256) void tsplit_k(
    const float* __restrict__ W, unsigned short* __restrict__ Th,
    unsigned short* __restrict__ Tl)
{
  __shared__ float t[64][68];
  int bi = blockIdx.x & 15, bj = blockIdx.x >> 4;
  int tid = threadIdx.x;
  int lr = tid >> 2, lc4 = tid & 3;
#pragma unroll
  for (int q = 0; q < 4; ++q) {
    int col = (lc4 + q * 4) * 4;
    f32x4 v = *(const f32x4*)(W + (long long)(bj * 64 + lr) * DD + bi * 64 + col);
    t[lr][col] = v[0]; t[lr][col + 1] = v[1];
    t[lr][col + 2] = v[2]; t[lr][col + 3] = v[3];
  }
  __syncthreads();
  int orow = tid >> 2, ch = tid & 3;
#pragma unroll
  for (int cc = 0; cc < 2; ++cc) {
    int c0 = (ch + cc * 4) * 8;
    bf16x8 h, l;
#pragma unroll
    for (int e = 0; e < 8; ++e) {
      float v = t[c0 + e][orow];
      unsigned short hh = f2bf(v);
      h[e] = (short)hh;
      l[e] = (short)f2bf(v - bf2f(hh));
    }
    long long o = (long long)(bi * 64 + orow) * DD + bj * 64 + c0;
    *(bf16x8*)(Th + o) = h;
    *(bf16x8*)(Tl + o) = l;
  }
}

// ---------------------------------------------------------------------------
// bt-GEMM (128^2, 2 M-tiles/block, depth-2 counted vmcnt) — R10/R11 verified.
// ---------------------------------------------------------------------------
template<int NMFMA, bool SPLIT_OUT>
__global__ __launch_bounds__(256, 2) void gemm_bt(
    const unsigned short* __restrict__ Ah_g, const unsigned short* __restrict__ Al_g,
    const unsigned short* __restrict__ Bh_g, const unsigned short* __restrict__ Bl_g,
    unsigned short* __restrict__ Chi, unsigned short* __restrict__ Clo,
    int Nn, int K,
    long long aStride, long long bStride, long long cStride,
    int tilesM, int tilesN)
{
  constexpr int HALF = (NMFMA == 3) ? 16384 : 8192;
  __shared__ short lds[2 * HALF];

  int tid = threadIdx.x;
  int lane = tid & 63, wid = tid >> 6;
  int wr = wid >> 1, wc = wid & 1;
  int l15 = lane & 15, lq = lane >> 4;

  int wg = xcd_swizzle(blockIdx.x, gridDim.x);
  int tilesM2 = tilesM >> 1;
  int tilesPer = tilesM2 * tilesN;
  int b = wg / tilesPer;
  int rem = wg % tilesPer;
  int mt2 = rem / tilesN, nt = rem % tilesN;

  const unsigned short* Bgh = Bh_g + (long long)b * bStride + (long long)nt * 128 * K;
  const unsigned short* Bgl = (NMFMA == 3) ? Bl_g + (long long)b * bStride + (long long)nt * 128 * K : nullptr;

  for (int hm = 0; hm < 2; ++hm) {
    int mt = mt2 + hm * tilesM2;
    const unsigned short* Agh = Ah_g + (long long)b * aStride + (long long)mt * 128 * K;
    const unsigned short* Agl = (NMFMA == 3) ? Al_g + (long long)b * aStride + (long long)mt * 128 * K : nullptr;

    f32x4 acc[4][4];
#pragma unroll
    for (int i = 0; i < 4; ++i)
#pragma unroll
      for (int j = 0; j < 4; ++j) acc[i][j] = (f32x4){0.f, 0.f, 0.f, 0.f};

    auto stage = [&](int t, int h) {
      int k0 = t * 32;
      if constexpr (NMFMA == 3) {
        stage_pair(Agh + k0, K, Agl + k0, K, lds + h * HALF, tid);
        stage_pair(Bgh + k0, K, Bgl + k0, K, lds + h * HALF + 8192, tid);
      } else {
        stage_pair(Agh + k0, K, Bgh + k0, K, lds + h * HALF, tid);
      }
    };
    auto compute = [&](int h) {
      __builtin_amdgcn_s_setprio(1);
      if constexpr (NMFMA == 3) {
        const short* U = lds + h * HALF;
        const short* V = U + 8192;
        bf16x8 afh[4], afl[4], bfh[4], bfl[4];
#pragma unroll
        for (int i = 0; i < 4; ++i) {
          int ra = wr * 64 + i * 16 + l15;
          int sa = (ra & 7) << 4;
          afh[i] = *(const bf16x8*)(&U[((ra * 128 + lq * 16) ^ sa) >> 1]);
          afl[i] = *(const bf16x8*)(&U[((ra * 128 + 64 + lq * 16) ^ sa) >> 1]);
          int rb = wc * 64 + i * 16 + l15;
          int sb = (rb & 7) << 4;
          bfh[i] = *(const bf16x8*)(&V[((rb * 128 + lq * 16) ^ sb) >> 1]);
          bfl[i] = *(const bf16x8*)(&V[((rb * 128 + 64 + lq * 16) ^ sb) >> 1]);
        }
#pragma unroll
        for (int i = 0; i < 4; ++i)
#pragma unroll
          for (int j = 0; j < 4; ++j) {
            acc[i][j] = __builtin_amdgcn_mfma_f32_16x16x32_bf16(afh[i], bfh[j], acc[i][j], 0, 0, 0);
            acc[i][j] = __builtin_amdgcn_mfma_f32_16x16x32_bf16(afh[i], bfl[j], acc[i][j], 0, 0, 0);
            acc[i][j] = __builtin_amdgcn_mfma_f32_16x16x32_bf16(afl[i], bfh[j], acc[i][j], 0, 0, 0);
          }
      } else {
        const short* W = lds + h * HALF;
        bf16x8 af[4], bfr[4];
#pragma unroll
        for (int i = 0; i < 4; ++i) {
          int ra = wr * 64 + i * 16 + l15;
          af[i] = *(const bf16x8*)(&W[((ra * 128 + lq * 16) ^ ((ra & 7) << 4)) >> 1]);
          int rb = wc * 64 + i * 16 + l15;
          bfr[i] = *(const bf16x8*)(&W[((rb * 128 + 64 + lq * 16) ^ ((rb & 7) << 4)) >> 1]);
        }
#pragma unroll
        for (int i = 0; i < 4; ++i)
#pragma unroll
          for (int j = 0; j < 4; ++j)
            acc[i][j] = __builtin_amdgcn_mfma_f32_16x16x32_bf16(af[i], bfr[j], acc[i][j], 0, 0, 0);
      }
      __builtin_amdgcn_s_setprio(0);
    };

    int NT = K >> 5;
    stage(0, 0);
    stage(1, 1);
    for (int t = 0; t < NT; ++t) {
      if (t < NT - 1) {
        if constexpr (NMFMA == 3) WAITBAR(8); else WAITBAR(4);
      } else {
        WAITBAR(0);
      }
      compute(t & 1);
      BAR();
      if (t + 2 < NT) stage(t + 2, t & 1);
    }

    unsigned short* ch = Chi + (long long)b * cStride;
    unsigned short* cl = SPLIT_OUT ? (Clo + (long long)b * cStride) : nullptr;
#pragma unroll
    for (int i = 0; i < 4; ++i)
#pragma unroll
      for (int j = 0; j < 4; ++j)
#pragma unroll
        for (int e = 0; e < 4; ++e) {
          int row = mt * 128 + wr * 64 + i * 16 + lq * 4 + e;
          int col = nt * 128 + wc * 64 + j * 16 + l15;
          float vv = acc[i][j][e];
          unsigned short h = f2bf(vv);
          ch[(long long)row * Nn + col] = h;
          if constexpr (SPLIT_OUT) cl[(long long)row * Nn + col] = f2bf(vv - bf2f(h));
        }
    BAR();
  }
}

// ---------------------------------------------------------------------------
// gemm256p8: 256^2 tile, BK=32, bf16x3, 8 waves (2x4), 128KB dbuf,
// 4-phase interleave per K-step + depth-2 counted vmcnt. Staging/fragment
// math identical to R12's verified gemm256.
// ---------------------------------------------------------------------------
template<bool SPLIT_OUT>
__global__ __launch_bounds__(512, 2) void gemm256p8(
    const unsigned short* __restrict__ Ah_g, const unsigned short* __restrict__ Al_g,
    const unsigned short* __restrict__ Bh_g, const unsigned short* __restrict__ Bl_g,
    unsigned short* __restrict__ Chi, unsigned short* __restrict__ Clo,
    int Nn, int K,
    long long aStride, long long bStride, long long cStride,
    int tilesM, int tilesN)
{
  __shared__ short lds[2 * 32768];   // 128KB: [A-combined 32KB | B-combined 32KB] x2

  int tid = threadIdx.x;
  int lane = tid & 63, wid = tid >> 6;
  int wr = wid >> 2, wc = wid & 3;
  int l15 = lane & 15, lq = lane >> 4;

  int wg = xcd_swizzle(blockIdx.x, gridDim.x);
  int tilesPer = tilesM * tilesN;
  int b = wg / tilesPer;
  int rem = wg % tilesPer;
  int mt = rem / tilesN, nt = rem % tilesN;

  const unsigned short* Agh = Ah_g + (long long)b * aStride + (long long)mt * 256 * K;
  const unsigned short* Agl = Al_g + (long long)b * aStride + (long long)mt * 256 * K;
  const unsigned short* Bgh = Bh_g + (long long)b * bStride + (long long)nt * 256 * K;
  const unsigned short* Bgl = Bl_g + (long long)b * bStride + (long long)nt * 256 * K;

  f32x4 acc[8][4];
#pragma unroll
  for (int i = 0; i < 8; ++i)
#pragma unroll
    for (int j = 0; j < 4; ++j) acc[i][j] = (f32x4){0.f, 0.f, 0.f, 0.f};

  // 512-thread staging of one 256-row combined plane (row = [hi 64B | lo 64B])
  auto stageP = [&](const unsigned short* p0, const unsigned short* p1,
                    int k0, short* dst) {
#pragma unroll
    for (int it = 0; it < 4; ++it) {
      int ii = it * 512 + tid;
      int r = ii >> 3;
      int c8 = (ii & 7) ^ (r & 7);
      const unsigned short* src = ((c8 < 4) ? p0 : p1) + (long long)r * K + k0 + (c8 & 3) * 8;
      gload16(src, &dst[ii * 8]);
    }
  };
  auto stage = [&](int t, int h) {
    int k0 = t * 32;
    stageP(Agh, Agl, k0, lds + h * 32768);
    stageP(Bgh, Bgl, k0, lds + h * 32768 + 16384);
  };

  int NT = K >> 5;   // 32
  stage(0, 0);
  stage(1, 1);
  for (int t = 0; t < NT; ++t) {
    int h = t & 1;
    if (t < NT - 1) WAITBAR(8); else WAITBAR(0);   // tile t landed, all waves
    const short* A = lds + h * 32768;
    const short* B = A + 16384;
#pragma unroll
    for (int ph = 0; ph < 4; ++ph) {
      const int ih = ph >> 1, jh = ph & 1;
      bf16x8 bh[2], bl[2], ah[4], al[4];
#pragma unroll
      for (int j = 0; j < 2; ++j) {
        int rb = wc * 64 + (jh * 2 + j) * 16 + l15;
        int sb = (rb & 7) << 4;
        bh[j] = *(const bf16x8*)(&B[((rb * 128 + lq * 16) ^ sb) >> 1]);
        bl[j] = *(const bf16x8*)(&B[((rb * 128 + 64 + lq * 16) ^ sb) >> 1]);
      }
#pragma unroll
      for (int i = 0; i < 4; ++i) {
        int ra = wr * 128 + (ih * 4 + i) * 16 + l15;
        int sa = (ra & 7) << 4;
        ah[i] = *(const bf16x8*)(&A[((ra * 128 + lq * 16) ^ sa) >> 1]);
        al[i] = *(const bf16x8*)(&A[((ra * 128 + 64 + lq * 16) ^ sa) >> 1]);
      }
      __builtin_amdgcn_s_setprio(1);
#pragma unroll
      for (int i = 0; i < 4; ++i)
#pragma unroll
        for (int j = 0; j < 2; ++j) {
          const int I = ih * 4 + i, J = jh * 2 + j;
          acc[I][J] = __builtin_amdgcn_mfma_f32_16x16x32_bf16(ah[i], bh[j], acc[I][J], 0, 0, 0);
          acc[I][J] = __builtin_amdgcn_mfma_f32_16x16x32_bf16(ah[i], bl[j], acc[I][J], 0, 0, 0);
          acc[I][J] = __builtin_amdgcn_mfma_f32_16x16x32_bf16(al[i], bh[j], acc[I][J], 0, 0, 0);
        }
      __builtin_amdgcn_s_setprio(0);
      BAR();   // phase edge (last one also fences buffer h reuse)
    }
    if (t + 2 < NT) stage(t + 2, h);   // safe: all waves past final BAR
  }

  unsigned short* ch = Chi + (long long)b * cStride;
  unsigned short* cl = SPLIT_OUT ? (Clo + (long long)b * cStride) : nullptr;
#pragma unroll
  for (int i = 0; i < 8; ++i)
#pragma unroll
    for (int j = 0; j < 4; ++j)
#pragma unroll
      for (int e = 0; e < 4; ++e) {
        int row = mt * 256 + wr * 128 + i * 16 + lq * 4 + e;
        int col = nt * 256 + wc * 64 + j * 16 + l15;
        float vv = acc[i][j][e];
        unsigned short h = f2bf(vv);
        ch[(long long)row * Nn + col] = h;
        if constexpr (SPLIT_OUT) cl[(long long)row * Nn + col] = f2bf(vv - bf2f(h));
      }
}

// ---------------------------------------------------------------------------
// QK^T: bf16x3, 128x128 lower-triangular tiles, packed output. (R10/R11)
// ---------------------------------------------------------------------------
__global__ __launch_bounds__(256, 2) void qk_bt(
    const unsigned short* __restrict__ qh, const unsigned short* __restrict__ ql,
    const unsigned short* __restrict__ kh, const unsigned short* __restrict__ kl,
    float* __restrict__ Sg)
{
  __shared__ short lds[2 * 16384];

  int tid = threadIdx.x;
  int lane = tid & 63, wid = tid >> 6;
  int wr = wid >> 1, wc = wid & 1;
  int l15 = lane & 15, lq = lane >> 4;

  int wg = xcd_swizzle(blockIdx.x, gridDim.x);
  int b = wg / 136;
  int idx = wg % 136;
  int st = (int)((sqrtf(8.f * (float)idx + 1.f) - 1.f) * 0.5f);
  while ((st + 1) * (st + 2) / 2 <= idx) ++st;
  while (st * (st + 1) / 2 > idx) --st;
  int tt = idx - st * (st + 1) / 2;

  const unsigned short* Agh = qh + (long long)b * SS * DD + (long long)st * 128 * DD;
  const unsigned short* Agl = ql + (long long)b * SS * DD + (long long)st * 128 * DD;
  const unsigned short* Bgh = kh + (long long)b * TT * DD + (long long)tt * 128 * DD;
  const unsigned short* Bgl = kl + (long long)b * TT * DD + (long long)tt * 128 * DD;

  f32x4 acc[4][4];
#pragma unroll
  for (int i = 0; i < 4; ++i)
#pragma unroll
    for (int j = 0; j < 4; ++j) acc[i][j] = (f32x4){0.f, 0.f, 0.f, 0.f};

  auto stage = [&](int t, int h) {
    int k0 = t * 32;
    stage_pair(Agh + k0, DD, Agl + k0, DD, lds + h * 16384, tid);
    stage_pair(Bgh + k0, DD, Bgl + k0, DD, lds + h * 16384 + 8192, tid);
  };
  auto compute = [&](int h) {
    __builtin_amdgcn_s_setprio(1);
    const short* U = lds + h * 16384;
    const short* V = U + 8192;
    bf16x8 afh[4], afl[4], bfh[4], bfl[4];
#pragma unroll
    for (int i = 0; i < 4; ++i) {
      int ra = wr * 64 + i * 16 + l15;
      int sa = (ra & 7) << 4;
      afh[i] = *(const bf16x8*)(&U[((ra * 128 + lq * 16) ^ sa) >> 1]);
      afl[i] = *(const bf16x8*)(&U[((ra * 128 + 64 + lq * 16) ^ sa) >> 1]);
      int rb = wc * 64 + i * 16 + l15;
      int sb = (rb & 7) << 4;
      bfh[i] = *(const bf16x8*)(&V[((rb * 128 + lq * 16) ^ sb) >> 1]);
      bfl[i] = *(const bf16x8*)(&V[((rb * 128 + 64 + lq * 16) ^ sb) >> 1]);
    }
#pragma unroll
    for (int i = 0; i < 4; ++i)
#pragma unroll
      for (int j = 0; j < 4; ++j) {
        acc[i][j] = __builtin_amdgcn_mfma_f32_16x16x32_bf16(afh[i], bfh[j], acc[i][j], 0, 0, 0);
        acc[i][j] = __builtin_amdgcn_mfma_f32_16x16x32_bf16(afh[i], bfl[j], acc[i][j], 0, 0, 0);
        acc[i][j] = __builtin_amdgcn_mfma_f32_16x16x32_bf16(afl[i], bfh[j], acc[i][j], 0, 0, 0);
      }
    __builtin_amdgcn_s_setprio(0);
  };

  stage(0, 0);
  stage(1, 1);
  for (int t = 0; t < 32; ++t) {
    if (t < 31) WAITBAR(8); else WAITBAR(0);
    compute(t & 1);
    BAR();
    if (t + 2 < 32) stage(t + 2, t & 1);
  }

  float* Sb = Sg + ((long long)b * 136 + idx) * TILE_E;
#pragma unroll
  for (int i = 0; i < 4; ++i)
#pragma unroll
    for (int j = 0; j < 4; ++j)
#pragma unroll
      for (int e = 0; e < 4; ++e) {
        int row = wr * 64 + i * 16 + lq * 4 + e;
        int col = wc * 64 + j * 16 + l15;
        Sb[(long long)row * 128 + col] = acc[i][j][e];
      }
}

// ---------------------------------------------------------------------------
// Row softmax over packed triangular tiles (causal, *32). P bf16 in place.
// ---------------------------------------------------------------------------
__global__ __launch_bounds__(256) void softmax_kernel(float* __restrict__ Sg)
{
  __shared__ float red[8];
  int blk = blockIdx.x;
  int b = blk >> 11, s = blk & 2047;
  int st = s >> 7, r = s & 127;
  long long tri = (long long)st * (st + 1) / 2;
  const float* tb = Sg + ((long long)b * 136 + tri) * TILE_E + (long long)r * 128;

  int tid = threadIdx.x;
  int lane = tid & 63, wid = tid >> 6;

  int c0 = tid * 8;
  int tt = c0 >> 7, cc = c0 & 127;
  bool live = (c0 <= s);
  f32x4 v0 = {0.f, 0.f, 0.f, 0.f}, v1 = {0.f, 0.f, 0.f, 0.f};
  if (live) {
    const float* seg = tb + (long long)tt * TILE_E + cc;
    v0 = *(const f32x4*)seg;
    v1 = *(const f32x4*)(seg + 4);
  }

  float m = -3.0e38f;
#pragma unroll
  for (int e = 0; e < 4; ++e) {
    if (c0 + e <= s) m = fmaxf(m, v0[e]);
    if (c0 + 4 + e <= s) m = fmaxf(m, v1[e]);
  }
#pragma unroll
  for (int o = 32; o > 0; o >>= 1) m = fmaxf(m, __shfl_xor(m, o));
  if (lane == 0) red[wid] = m;
  __syncthreads();
  m = fmaxf(fmaxf(red[0], red[1]), fmaxf(red[2], red[3]));

  const float C = 46.16624130844683f;  // 32 * log2(e)
  float p0[4], p1[4];
  float sum = 0.f;
#pragma unroll
  for (int e = 0; e < 4; ++e) {
    p0[e] = (c0 + e <= s) ? exp2f((v0[e] - m) * C) : 0.f;
    sum += p0[e];
    p1[e] = (c0 + 4 + e <= s) ? exp2f((v1[e] - m) * C) : 0.f;
    sum += p1[e];
  }
#pragma unroll
  for (int o = 32; o > 0; o >>= 1) sum += __shfl_xor(sum, o);
  if (lane == 0) red[4 + wid] = sum;
  __syncthreads();
  float inv = 1.f / (red[4] + red[5] + red[6] + red[7]);

  union { bf16x8 v; s16x4 h[2]; } w;
#pragma unroll
  for (int e = 0; e < 4; ++e) {
    w.h[0][e] = (short)f2bf(p0[e] * inv);
    w.h[1][e] = (short)f2bf(p1[e] * inv);
  }
  __syncthreads();
  if (c0 < (st + 1) * 128) {
    unsigned short* pw = (unsigned short*)Sg +
        (((long long)b * 136 + tri + tt) * TILE_E) * 2 + (long long)r * 256 + cc;
    *(bf16x8*)pw = w.v;
  }
}

// ---------------------------------------------------------------------------
// PV: O[s,d] = sum_t P[s,t]*vT[d,t]. Counted-vmcnt depth-2; longest first.
// ---------------------------------------------------------------------------
__global__ __launch_bounds__(256, 2) void pv_bt(
    const unsigned short* __restrict__ P, const unsigned short* __restrict__ vT,
    float* __restrict__ Out)
{
  __shared__ short lds[2 * 8192];

  int tid = threadIdx.x;
  int lane = tid & 63, wid = tid >> 6;
  int wr = wid >> 1, wc = wid & 1;
  int l15 = lane & 15, lq = lane >> 4;

  int wg = xcd_swizzle(blockIdx.x, gridDim.x);
  int b = wg >> 7;
  int rem = wg & 127;
  int st = 15 - (rem >> 3);
  int dt = rem & 7;

  const unsigned short* Ps = P + ((long long)b * 136 + (long long)st * (st + 1) / 2) * (TILE_E * 2);
  const unsigned short* Vb = vT + (long long)b * DD * TT + (long long)dt * 128 * TT;
  int NT = (st + 1) * 4;

  f32x4 acc[4][4];
#pragma unroll
  for (int i = 0; i < 4; ++i)
#pragma unroll
    for (int j = 0; j < 4; ++j) acc[i][j] = (f32x4){0.f, 0.f, 0.f, 0.f};

  auto stage = [&](int t, int h) {
    int t0 = t * 32;
    const unsigned short* s0 = Ps + (long long)(t0 >> 7) * (TILE_E * 2) + (t0 & 127);
    stage_pair(s0, 256, Vb + t0, TT, lds + h * 8192, tid);
  };
  auto compute = [&](int h) {
    __builtin_amdgcn_s_setprio(1);
    const short* W = lds + h * 8192;
    bf16x8 af[4], bfr[4];
#pragma unroll
    for (int i = 0; i < 4; ++i) {
      int ra = wr * 64 + i * 16 + l15;
      af[i] = *(const bf16x8*)(&W[((ra * 128 + lq * 16) ^ ((ra & 7) << 4)) >> 1]);
      int rb = wc * 64 + i * 16 + l15;
      bfr[i] = *(const bf16x8*)(&W[((rb * 128 + 64 + lq * 16) ^ ((rb & 7) << 4)) >> 1]);
    }
#pragma unroll
    for (int i = 0; i < 4; ++i)
#pragma unroll
      for (int j = 0; j < 4; ++j)
        acc[i][j] = __builtin_amdgcn_mfma_f32_16x16x32_bf16(af[i], bfr[j], acc[i][j], 0, 0, 0);
    __builtin_amdgcn_s_setprio(0);
  };

  stage(0, 0);
  stage(1, 1);
  for (int t = 0; t < NT; ++t) {
    if (t < NT - 1) WAITBAR(4); else WAITBAR(0);
    compute(t & 1);
    BAR();
    if (t + 2 < NT) stage(t + 2, t & 1);
  }

  float* Ob = Out + (long long)b * SS * DD;
#pragma unroll
  for (int i = 0; i < 4; ++i)
#pragma unroll
    for (int j = 0; j < 4; ++j)
#pragma unroll
      for (int e = 0; e < 4; ++e) {
        int row = st * 128 + wr * 64 + i * 16 + lq * 4 + e;
        int col = dt * 128 + wc * 64 + j * 16 + l15;
        Ob[(long long)row * DD + col] = acc[i][j][e];
      }
}

// ---------------------------------------------------------------------------
extern "C" void kernel_launch(void* const* d_in, const int* in_sizes, int n_in,
                              void* d_out, int out_size, void* d_ws, size_t ws_size,
                              hipStream_t stream) {
  (void)in_sizes; (void)n_in; (void)out_size;
  const float* key   = (const float*)d_in[0];
  const float* query = (const float*)d_in[1];
  const float* value = (const float*)d_in[2];
  const float* Wq    = (const float*)d_in[3];
  const float* Wk    = (const float*)d_in[4];
  const float* Wv    = (const float*)d_in[5];
  float* Out = (float*)d_out;

  const long long SD = (long long)SS * DD;
  const long long DT = (long long)DD * TT;
  const long long WN = (long long)DD * DD;

  const unsigned long long PLANE_B  = (unsigned long long)SD * 2;
  const unsigned long long WPLANE_B = (unsigned long long)WN * 2;
  const unsigned long long SCORE_B  = 136ull * TILE_E * 4;

  auto need = [&](int g) -> unsigned long long {
    return 3ull * WPLANE_B + (unsigned long long)g * (SCORE_B + 5ull * PLANE_B);
  };
  int G = 1;
  for (int g : {8, 4, 2, 1}) if (ws_size >= need(g)) { G = g; break; }

  char* ws = (char*)d_ws;
  size_t off = 0;
  auto alloc = [&](unsigned long long bytes) { char* p = ws + off; off += bytes; return p; };

  unsigned short* mph = (unsigned short*)alloc(WPLANE_B);
  unsigned short* mpl = (unsigned short*)alloc(WPLANE_B);
  unsigned short* wvh = (unsigned short*)alloc(WPLANE_B);
  char* slab = alloc((unsigned long long)G * SCORE_B);
  unsigned short* qh  = (unsigned short*)alloc((unsigned long long)G * PLANE_B);
  unsigned short* ql  = (unsigned short*)alloc((unsigned long long)G * PLANE_B);
  unsigned short* kh  = (unsigned short*)alloc((unsigned long long)G * PLANE_B);
  unsigned short* kl  = (unsigned short*)alloc((unsigned long long)G * PLANE_B);
  unsigned short* vT  = (unsigned short*)alloc((unsigned long long)G * PLANE_B);

  unsigned short* wqTh = (unsigned short*)slab;
  unsigned short* wqTl = (unsigned short*)(slab + WPLANE_B);
  unsigned short* wkTh = (unsigned short*)(slab + 2 * WPLANE_B);
  unsigned short* wkTl = (unsigned short*)(slab + 3 * WPLANE_B);

  unsigned short* iah = (unsigned short*)slab;
  unsigned short* ial = (unsigned short*)(slab + (unsigned long long)G * PLANE_B);
  float* Sg = (float*)slab;

  // M' = Wk^T Wq (hi+lo), tiny 1024^3
  tsplit_k<<<256, 256, 0, stream>>>(Wq, wqTh, wqTl);
  tsplit_k<<<256, 256, 0, stream>>>(Wk, wkTh, wkTl);
  split_h_k<<<512, 256, 0, stream>>>(Wv, wvh, WN / 4);
  gemm_bt<3, true><<<32, 256, 0, stream>>>(
      wkTh, wkTl, wqTh, wqTl, mph, mpl, DD, DD, 0, 0, 0, 8, 8);

  for (int b0 = 0; b0 < NB; b0 += G) {
    long long n4 = (long long)G * SD / 4;
    // z = x M'^T : 8-phase 256^2 core, grid G*32 = 256 = 1 block/CU
    split_hl_k<<<2048, 256, 0, stream>>>(query + (long long)b0 * SD, iah, ial, n4);
    gemm256p8<true><<<G * 32, 512, 0, stream>>>(
        iah, ial, mph, mpl, qh, ql, DD, DD, SD, 0, SD, 8, 4);
    // key: exact hi/lo split (B operand of the score GEMM)
    split_hl_k<<<2048, 256, 0, stream>>>(key + (long long)b0 * SD, kh, kl, n4);
    // vT = Wv @ value^T (128^2 core, 2-Mtile blocks, grid G*64 = 512)
    split_h_k<<<2048, 256, 0, stream>>>(value + (long long)b0 * SD, iah, n4);
    gemm_bt<1, false><<<G * 64, 256, 0, stream>>>(
        wvh, nullptr, iah, nullptr, vT, nullptr, TT, DD, 0, SD, DT, 8, 16);
    // scores = z key^T (triangular), softmax, PV
    qk_bt<<<G * 136, 256, 0, stream>>>(qh, ql, kh, kl, Sg);
    softmax_kernel<<<G * SS, 256, 0, stream>>>(Sg);
    pv_bt<<<G * 128, 256, 0, stream>>>(
        (const unsigned short*)Sg, vT, Out + (long long)b0 * SD);
  }
}

// Round 14
// 480.225 us; speedup vs baseline: 1.0526x; 1.0356x over previous
//
#include <hip/hip_runtime.h>
#include <hip/hip_bf16.h>

// AttentionLayer: out = softmax(32 * (xWq^T)(yWk^T)^T + causal) @ (zWv^T)
// N=8, S=T=2048, D=1024. All f32 in/out.
//
// R14: issue-early staging (T14) in all GEMM K-loops. R10-R13 analysis:
// the 2-barrier loop stalls ~200cy/iter because stage(t+2) issued AFTER
// the MFMA burst leaves < HBM latency (~900cy) before its WAITBAR.
// New per-iter order: WAITBAR -> ds_reads -> BAR -> stage(t+2) -> MFMA.
// Same barrier count, buffer dead at stage time (reads barriered), loads
// fly during the MFMA burst. z-proj/M' reverted to 128^2 gemm_bt (256^2
// variants R12/R13 proven neutral). Fold scores = x(Wk^T Wq)y^T (R11).

typedef __attribute__((ext_vector_type(4))) float f32x4;
typedef __attribute__((ext_vector_type(8))) short bf16x8;
typedef __attribute__((ext_vector_type(4))) short s16x4;

#define DEVI __device__ __forceinline__

DEVI unsigned short f2bf(float x) {
  union { float f; unsigned u; } v; v.f = x;
  unsigned r = v.u + 0x7FFFu + ((v.u >> 16) & 1u);
  return (unsigned short)(r >> 16);
}
DEVI float bf2f(unsigned short b) {
  union { float f; unsigned u; } v; v.u = ((unsigned)b) << 16;
  return v.f;
}

DEVI void gload16(const void* g, void* l) {
#if __has_builtin(__builtin_amdgcn_global_load_lds)
  typedef __attribute__((address_space(1))) const unsigned int* gas_u32;
  typedef __attribute__((address_space(3))) unsigned int* las_u32;
  __builtin_amdgcn_global_load_lds(
      (gas_u32)(unsigned long long)g,
      (las_u32)(unsigned int)(unsigned long long)l, 16, 0, 0);
#else
  *(bf16x8*)l = *(const bf16x8*)g;
#endif
}

DEVI int xcd_swizzle(int bid, int nwg) {
  if (nwg & 7) return bid;
  int cpx = nwg >> 3;
  return (bid & 7) * cpx + (bid >> 3);
}

#define WAITBAR(N) asm volatile("s_waitcnt vmcnt(" #N ")\ns_barrier" ::: "memory")
#define BAR()      asm volatile("s_barrier" ::: "memory")

// Stage one combined plane: 128 rows x 128B, row = [s0 64B | s1 64B],
// XOR-swizzled (chunk ^= row&7), linear LDS dest (256-thread blocks).
DEVI void stage_pair(const unsigned short* __restrict__ s0, long long rs0,
                     const unsigned short* __restrict__ s1, long long rs1,
                     short* lds, int tid) {
#pragma unroll
  for (int it = 0; it < 4; ++it) {
    int ii = it * 256 + tid;
    int r = ii >> 3;
    int c8 = (ii & 7) ^ (r & 7);
    const unsigned short* src = (c8 < 4)
        ? s0 + (long long)r * rs0 + (c8 & 3) * 8
        : s1 + (long long)r * rs1 + (c8 & 3) * 8;
    gload16(src, &lds[ii * 8]);
  }
}

constexpr int NB = 8, SS = 2048, TT = 2048, DD = 1024;
constexpr long long TILE_E = 16384;

// ---------------------------------------------------------------------------
// Elementwise split kernels.
// ---------------------------------------------------------------------------
__global__ __launch_bounds__(256) void split_hl_k(
    const float* __restrict__ in, unsigned short* __restrict__ hi,
    unsigned short* __restrict__ lo, long long n4)
{
  long long i = (long long)blockIdx.x * 256 + threadIdx.x;
  long long stride = (long long)gridDim.x * 256;
  for (; i < n4; i += stride) {
    f32x4 v = ((const f32x4*)in)[i];
    s16x4 h, l;
#pragma unroll
    for (int e = 0; e < 4; ++e) {
      unsigned short hh = f2bf(v[e]);
      h[e] = (short)hh;
      l[e] = (short)f2bf(v[e] - bf2f(hh));
    }
    ((s16x4*)hi)[i] = h;
    ((s16x4*)lo)[i] = l;
  }
}

__global__ __launch_bounds__(256) void split_h_k(
    const float* __restrict__ in, unsigned short* __restrict__ hi, long long n4)
{
  long long i = (long long)blockIdx.x * 256 + threadIdx.x;
  long long stride = (long long)gridDim.x * 256;
  for (; i < n4; i += stride) {
    f32x4 v = ((const f32x4*)in)[i];
    s16x4 h;
#pragma unroll
    for (int e = 0; e < 4; ++e) h[e] = (short)f2bf(v[e]);
    ((s16x4*)hi)[i] = h;
  }
}

// Transpose + split weights (tiny).
__global__ __launch_bounds__(256) void tsplit_k(
    const float* __restrict__ W, unsigned short* __restrict__ Th,
    unsigned short* __restrict__ Tl)
{
  __shared__ float t[64][68];
  int bi = blockIdx.x & 15, bj = blockIdx.x >> 4;
  int tid = threadIdx.x;
  int lr = tid >> 2, lc4 = tid & 3;
#pragma unroll
  for (int q = 0; q < 4; ++q) {
    int col = (lc4 + q * 4) * 4;
    f32x4 v = *(const f32x4*)(W + (long long)(bj * 64 + lr) * DD + bi * 64 + col);
    t[lr][col] = v[0]; t[lr][col + 1] = v[1];
    t[lr][col + 2] = v[2]; t[lr][col + 3] = v[3];
  }
  __syncthreads();
  int orow = tid >> 2, ch = tid & 3;
#pragma unroll
  for (int cc = 0; cc < 2; ++cc) {
    int c0 = (ch + cc * 4) * 8;
    bf16x8 h, l;
#pragma unroll
    for (int e = 0; e < 8; ++e) {
      float v = t[c0 + e][orow];
      unsigned short hh = f2bf(v);
      h[e] = (short)hh;
      l[e] = (short)f2bf(v - bf2f(hh));
    }
    long long o = (long long)(bi * 64 + orow) * DD + bj * 64 + c0;
    *(bf16x8*)(Th + o) = h;
    *(bf16x8*)(Tl + o) = l;
  }
}

// ---------------------------------------------------------------------------
// bt-GEMM (128^2, 2 M-tiles/block, depth-2 counted vmcnt, ISSUE-EARLY stage).
// ---------------------------------------------------------------------------
template<int NMFMA, bool SPLIT_OUT>
__global__ __launch_bounds__(256, 2) void gemm_bt(
    const unsigned short* __restrict__ Ah_g, const unsigned short* __restrict__ Al_g,
    const unsigned short* __restrict__ Bh_g, const unsigned short* __restrict__ Bl_g,
    unsigned short* __restrict__ Chi, unsigned short* __restrict__ Clo,
    int Nn, int K,
    long long aStride, long long bStride, long long cStride,
    int tilesM, int tilesN)
{
  constexpr int HALF = (NMFMA == 3) ? 16384 : 8192;
  __shared__ short lds[2 * HALF];

  int tid = threadIdx.x;
  int lane = tid & 63, wid = tid >> 6;
  int wr = wid >> 1, wc = wid & 1;
  int l15 = lane & 15, lq = lane >> 4;

  int wg = xcd_swizzle(blockIdx.x, gridDim.x);
  int tilesM2 = tilesM >> 1;
  int tilesPer = tilesM2 * tilesN;
  int b = wg / tilesPer;
  int rem = wg % tilesPer;
  int mt2 = rem / tilesN, nt = rem % tilesN;

  const unsigned short* Bgh = Bh_g + (long long)b * bStride + (long long)nt * 128 * K;
  const unsigned short* Bgl = (NMFMA == 3) ? Bl_g + (long long)b * bStride + (long long)nt * 128 * K : nullptr;

  for (int hm = 0; hm < 2; ++hm) {
    int mt = mt2 + hm * tilesM2;
    const unsigned short* Agh = Ah_g + (long long)b * aStride + (long long)mt * 128 * K;
    const unsigned short* Agl = (NMFMA == 3) ? Al_g + (long long)b * aStride + (long long)mt * 128 * K : nullptr;

    f32x4 acc[4][4];
#pragma unroll
    for (int i = 0; i < 4; ++i)
#pragma unroll
      for (int j = 0; j < 4; ++j) acc[i][j] = (f32x4){0.f, 0.f, 0.f, 0.f};

    auto stage = [&](int t, int h) {
      int k0 = t * 32;
      if constexpr (NMFMA == 3) {
        stage_pair(Agh + k0, K, Agl + k0, K, lds + h * HALF, tid);
        stage_pair(Bgh + k0, K, Bgl + k0, K, lds + h * HALF + 8192, tid);
      } else {
        stage_pair(Agh + k0, K, Bgh + k0, K, lds + h * HALF, tid);
      }
    };

    int NT = K >> 5;
    stage(0, 0);
    stage(1, 1);
    for (int t = 0; t < NT; ++t) {
      int h = t & 1;
      if (t < NT - 1) {
        if constexpr (NMFMA == 3) WAITBAR(8); else WAITBAR(4);
      } else {
        WAITBAR(0);
      }
      if constexpr (NMFMA == 3) {
        const short* U = lds + h * HALF;
        const short* V = U + 8192;
        bf16x8 afh[4], afl[4], bfh[4], bfl[4];
#pragma unroll
        for (int i = 0; i < 4; ++i) {
          int ra = wr * 64 + i * 16 + l15;
          int sa = (ra & 7) << 4;
          afh[i] = *(const bf16x8*)(&U[((ra * 128 + lq * 16) ^ sa) >> 1]);
          afl[i] = *(const bf16x8*)(&U[((ra * 128 + 64 + lq * 16) ^ sa) >> 1]);
          int rb = wc * 64 + i * 16 + l15;
          int sb = (rb & 7) << 4;
          bfh[i] = *(const bf16x8*)(&V[((rb * 128 + lq * 16) ^ sb) >> 1]);
          bfl[i] = *(const bf16x8*)(&V[((rb * 128 + 64 + lq * 16) ^ sb) >> 1]);
        }
        BAR();                         // all waves done reading buffer h
        if (t + 2 < NT) stage(t + 2, h);  // loads fly during MFMA burst
        __builtin_amdgcn_s_setprio(1);
#pragma unroll
        for (int i = 0; i < 4; ++i)
#pragma unroll
          for (int j = 0; j < 4; ++j) {
            acc[i][j] = __builtin_amdgcn_mfma_f32_16x16x32_bf16(afh[i], bfh[j], acc[i][j], 0, 0, 0);
            acc[i][j] = __builtin_amdgcn_mfma_f32_16x16x32_bf16(afh[i], bfl[j], acc[i][j], 0, 0, 0);
            acc[i][j] = __builtin_amdgcn_mfma_f32_16x16x32_bf16(afl[i], bfh[j], acc[i][j], 0, 0, 0);
          }
        __builtin_amdgcn_s_setprio(0);
      } else {
        const short* W = lds + h * HALF;
        bf16x8 af[4], bfr[4];
#pragma unroll
        for (int i = 0; i < 4; ++i) {
          int ra = wr * 64 + i * 16 + l15;
          af[i] = *(const bf16x8*)(&W[((ra * 128 + lq * 16) ^ ((ra & 7) << 4)) >> 1]);
          int rb = wc * 64 + i * 16 + l15;
          bfr[i] = *(const bf16x8*)(&W[((rb * 128 + 64 + lq * 16) ^ ((rb & 7) << 4)) >> 1]);
        }
        BAR();
        if (t + 2 < NT) stage(t + 2, h);
        __builtin_amdgcn_s_setprio(1);
#pragma unroll
        for (int i = 0; i < 4; ++i)
#pragma unroll
          for (int j = 0; j < 4; ++j)
            acc[i][j] = __builtin_amdgcn_mfma_f32_16x16x32_bf16(af[i], bfr[j], acc[i][j], 0, 0, 0);
        __builtin_amdgcn_s_setprio(0);
      }
    }

    unsigned short* ch = Chi + (long long)b * cStride;
    unsigned short* cl = SPLIT_OUT ? (Clo + (long long)b * cStride) : nullptr;
#pragma unroll
    for (int i = 0; i < 4; ++i)
#pragma unroll
      for (int j = 0; j < 4; ++j)
#pragma unroll
        for (int e = 0; e < 4; ++e) {
          int row = mt * 128 + wr * 64 + i * 16 + lq * 4 + e;
          int col = nt * 128 + wc * 64 + j * 16 + l15;
          float vv = acc[i][j][e];
          unsigned short h = f2bf(vv);
          ch[(long long)row * Nn + col] = h;
          if constexpr (SPLIT_OUT) cl[(long long)row * Nn + col] = f2bf(vv - bf2f(h));
        }
    BAR();  // LDS reuse safe across the two tiles
  }
}

// ---------------------------------------------------------------------------
// QK^T: bf16x3, 128x128 lower-triangular tiles, packed output. Issue-early.
// ---------------------------------------------------------------------------
__global__ __launch_bounds__(256, 2) void qk_bt(
    const unsigned short* __restrict__ qh, const unsigned short* __restrict__ ql,
    const unsigned short* __restrict__ kh, const unsigned short* __restrict__ kl,
    float* __restrict__ Sg)
{
  __shared__ short lds[2 * 16384];

  int tid = threadIdx.x;
  int lane = tid & 63, wid = tid >> 6;
  int wr = wid >> 1, wc = wid & 1;
  int l15 = lane & 15, lq = lane >> 4;

  int wg = xcd_swizzle(blockIdx.x, gridDim.x);
  int b = wg / 136;
  int idx = wg % 136;
  int st = (int)((sqrtf(8.f * (float)idx + 1.f) - 1.f) * 0.5f);
  while ((st + 1) * (st + 2) / 2 <= idx) ++st;
  while (st * (st + 1) / 2 > idx) --st;
  int tt = idx - st * (st + 1) / 2;

  const unsigned short* Agh = qh + (long long)b * SS * DD + (long long)st * 128 * DD;
  const unsigned short* Agl = ql + (long long)b * SS * DD + (long long)st * 128 * DD;
  const unsigned short* Bgh = kh + (long long)b * TT * DD + (long long)tt * 128 * DD;
  const unsigned short* Bgl = kl + (long long)b * TT * DD + (long long)tt * 128 * DD;

  f32x4 acc[4][4];
#pragma unroll
  for (int i = 0; i < 4; ++i)
#pragma unroll
    for (int j = 0; j < 4; ++j) acc[i][j] = (f32x4){0.f, 0.f, 0.f, 0.f};

  auto stage = [&](int t, int h) {
    int k0 = t * 32;
    stage_pair(Agh + k0, DD, Agl + k0, DD, lds + h * 16384, tid);
    stage_pair(Bgh + k0, DD, Bgl + k0, DD, lds + h * 16384 + 8192, tid);
  };

  stage(0, 0);
  stage(1, 1);
  for (int t = 0; t < 32; ++t) {
    int h = t & 1;
    if (t < 31) WAITBAR(8); else WAITBAR(0);
    const short* U = lds + h * 16384;
    const short* V = U + 8192;
    bf16x8 afh[4], afl[4], bfh[4], bfl[4];
#pragma unroll
    for (int i = 0; i < 4; ++i) {
      int ra = wr * 64 + i * 16 + l15;
      int sa = (ra & 7) << 4;
      afh[i] = *(const bf16x8*)(&U[((ra * 128 + lq * 16) ^ sa) >> 1]);
      afl[i] = *(const bf16x8*)(&U[((ra * 128 + 64 + lq * 16) ^ sa) >> 1]);
      int rb = wc * 64 + i * 16 + l15;
      int sb = (rb & 7) << 4;
      bfh[i] = *(const bf16x8*)(&V[((rb * 128 + lq * 16) ^ sb) >> 1]);
      bfl[i] = *(const bf16x8*)(&V[((rb * 128 + 64 + lq * 16) ^ sb) >> 1]);
    }
    BAR();                        // buffer h fully read by all waves
    if (t + 2 < 32) stage(t + 2, h);   // prefetch overlaps MFMA burst
    __builtin_amdgcn_s_setprio(1);
#pragma unroll
    for (int i = 0; i < 4; ++i)
#pragma unroll
      for (int j = 0; j < 4; ++j) {
        acc[i][j] = __builtin_amdgcn_mfma_f32_16x16x32_bf16(afh[i], bfh[j], acc[i][j], 0, 0, 0);
        acc[i][j] = __builtin_amdgcn_mfma_f32_16x16x32_bf16(afh[i], bfl[j], acc[i][j], 0, 0, 0);
        acc[i][j] = __builtin_amdgcn_mfma_f32_16x16x32_bf16(afl[i], bfh[j], acc[i][j], 0, 0, 0);
      }
    __builtin_amdgcn_s_setprio(0);
  }

  float* Sb = Sg + ((long long)b * 136 + idx) * TILE_E;
#pragma unroll
  for (int i = 0; i < 4; ++i)
#pragma unroll
    for (int j = 0; j < 4; ++j)
#pragma unroll
      for (int e = 0; e < 4; ++e) {
        int row = wr * 64 + i * 16 + lq * 4 + e;
        int col = wc * 64 + j * 16 + l15;
        Sb[(long long)row * 128 + col] = acc[i][j][e];
      }
}

// ---------------------------------------------------------------------------
// Row softmax over packed triangular tiles (causal, *32). P bf16 in place.
// ---------------------------------------------------------------------------
__global__ __launch_bounds__(256) void softmax_kernel(float* __restrict__ Sg)
{
  __shared__ float red[8];
  int blk = blockIdx.x;
  int b = blk >> 11, s = blk & 2047;
  int st = s >> 7, r = s & 127;
  long long tri = (long long)st * (st + 1) / 2;
  const float* tb = Sg + ((long long)b * 136 + tri) * TILE_E + (long long)r * 128;

  int tid = threadIdx.x;
  int lane = tid & 63, wid = tid >> 6;

  int c0 = tid * 8;
  int tt = c0 >> 7, cc = c0 & 127;
  bool live = (c0 <= s);
  f32x4 v0 = {0.f, 0.f, 0.f, 0.f}, v1 = {0.f, 0.f, 0.f, 0.f};
  if (live) {
    const float* seg = tb + (long long)tt * TILE_E + cc;
    v0 = *(const f32x4*)seg;
    v1 = *(const f32x4*)(seg + 4);
  }

  float m = -3.0e38f;
#pragma unroll
  for (int e = 0; e < 4; ++e) {
    if (c0 + e <= s) m = fmaxf(m, v0[e]);
    if (c0 + 4 + e <= s) m = fmaxf(m, v1[e]);
  }
#pragma unroll
  for (int o = 32; o > 0; o >>= 1) m = fmaxf(m, __shfl_xor(m, o));
  if (lane == 0) red[wid] = m;
  __syncthreads();
  m = fmaxf(fmaxf(red[0], red[1]), fmaxf(red[2], red[3]));

  const float C = 46.16624130844683f;  // 32 * log2(e)
  float p0[4], p1[4];
  float sum = 0.f;
#pragma unroll
  for (int e = 0; e < 4; ++e) {
    p0[e] = (c0 + e <= s) ? exp2f((v0[e] - m) * C) : 0.f;
    sum += p0[e];
    p1[e] = (c0 + 4 + e <= s) ? exp2f((v1[e] - m) * C) : 0.f;
    sum += p1[e];
  }
#pragma unroll
  for (int o = 32; o > 0; o >>= 1) sum += __shfl_xor(sum, o);
  if (lane == 0) red[4 + wid] = sum;
  __syncthreads();
  float inv = 1.f / (red[4] + red[5] + red[6] + red[7]);

  union { bf16x8 v; s16x4 h[2]; } w;
#pragma unroll
  for (int e = 0; e < 4; ++e) {
    w.h[0][e] = (short)f2bf(p0[e] * inv);
    w.h[1][e] = (short)f2bf(p1[e] * inv);
  }
  __syncthreads();
  if (c0 < (st + 1) * 128) {
    unsigned short* pw = (unsigned short*)Sg +
        (((long long)b * 136 + tri + tt) * TILE_E) * 2 + (long long)r * 256 + cc;
    *(bf16x8*)pw = w.v;
  }
}

// ---------------------------------------------------------------------------
// PV: O[s,d] = sum_t P[s,t]*vT[d,t]. Issue-early depth-2; longest first.
// ---------------------------------------------------------------------------
__global__ __launch_bounds__(256, 2) void pv_bt(
    const unsigned short* __restrict__ P, const unsigned short* __restrict__ vT,
    float* __restrict__ Out)
{
  __shared__ short lds[2 * 8192];

  int tid = threadIdx.x;
  int lane = tid & 63, wid = tid >> 6;
  int wr = wid >> 1, wc = wid & 1;
  int l15 = lane & 15, lq = lane >> 4;

  int wg = xcd_swizzle(blockIdx.x, gridDim.x);
  int b = wg >> 7;
  int rem = wg & 127;
  int st = 15 - (rem >> 3);
  int dt = rem & 7;

  const unsigned short* Ps = P + ((long long)b * 136 + (long long)st * (st + 1) / 2) * (TILE_E * 2);
  const unsigned short* Vb = vT + (long long)b * DD * TT + (long long)dt * 128 * TT;
  int NT = (st + 1) * 4;

  f32x4 acc[4][4];
#pragma unroll
  for (int i = 0; i < 4; ++i)
#pragma unroll
    for (int j = 0; j < 4; ++j) acc[i][j] = (f32x4){0.f, 0.f, 0.f, 0.f};

  auto stage = [&](int t, int h) {
    int t0 = t * 32;
    const unsigned short* s0 = Ps + (long long)(t0 >> 7) * (TILE_E * 2) + (t0 & 127);
    stage_pair(s0, 256, Vb + t0, TT, lds + h * 8192, tid);
  };

  stage(0, 0);
  stage(1, 1);
  for (int t = 0; t < NT; ++t) {
    int h = t & 1;
    if (t < NT - 1) WAITBAR(4); else WAITBAR(0);
    const short* W = lds + h * 8192;
    bf16x8 af[4], bfr[4];
#pragma unroll
    for (int i = 0; i < 4; ++i) {
      int ra = wr * 64 + i * 16 + l15;
      af[i] = *(const bf16x8*)(&W[((ra * 128 + lq * 16) ^ ((ra & 7) << 4)) >> 1]);
      int rb = wc * 64 + i * 16 + l15;
      bfr[i] = *(const bf16x8*)(&W[((rb * 128 + 64 + lq * 16) ^ ((rb & 7) << 4)) >> 1]);
    }
    BAR();
    if (t + 2 < NT) stage(t + 2, h);
    __builtin_amdgcn_s_setprio(1);
#pragma unroll
    for (int i = 0; i < 4; ++i)
#pragma unroll
      for (int j = 0; j < 4; ++j)
        acc[i][j] = __builtin_amdgcn_mfma_f32_16x16x32_bf16(af[i], bfr[j], acc[i][j], 0, 0, 0);
    __builtin_amdgcn_s_setprio(0);
  }

  float* Ob = Out + (long long)b * SS * DD;
#pragma unroll
  for (int i = 0; i < 4; ++i)
#pragma unroll
    for (int j = 0; j < 4; ++j)
#pragma unroll
      for (int e = 0; e < 4; ++e) {
        int row = st * 128 + wr * 64 + i * 16 + lq * 4 + e;
        int col = dt * 128 + wc * 64 + j * 16 + l15;
        Ob[(long long)row * DD + col] = acc[i][j][e];
      }
}

// ---------------------------------------------------------------------------
extern "C" void kernel_launch(void* const* d_in, const int* in_sizes, int n_in,
                              void* d_out, int out_size, void* d_ws, size_t ws_size,
                              hipStream_t stream) {
  (void)in_sizes; (void)n_in; (void)out_size;
  const float* key   = (const float*)d_in[0];
  const float* query = (const float*)d_in[1];
  const float* value = (const float*)d_in[2];
  const float* Wq    = (const float*)d_in[3];
  const float* Wk    = (const float*)d_in[4];
  const float* Wv    = (const float*)d_in[5];
  float* Out = (float*)d_out;

  const long long SD = (long long)SS * DD;
  const long long DT = (long long)DD * TT;
  const long long WN = (long long)DD * DD;

  const unsigned long long PLANE_B  = (unsigned long long)SD * 2;
  const unsigned long long WPLANE_B = (unsigned long long)WN * 2;
  const unsigned long long SCORE_B  = 136ull * TILE_E * 4;

  auto need = [&](int g) -> unsigned long long {
    return 3ull * WPLANE_B + (unsigned long long)g * (SCORE_B + 5ull * PLANE_B);
  };
  int G = 1;
  for (int g : {8, 4, 2, 1}) if (ws_size >= need(g)) { G = g; break; }

  char* ws = (char*)d_ws;
  size_t off = 0;
  auto alloc = [&](unsigned long long bytes) { char* p = ws + off; off += bytes; return p; };

  unsigned short* mph = (unsigned short*)alloc(WPLANE_B);
  unsigned short* mpl = (unsigned short*)alloc(WPLANE_B);
  unsigned short* wvh = (unsigned short*)alloc(WPLANE_B);
  char* slab = alloc((unsigned long long)G * SCORE_B);
  unsigned short* qh  = (unsigned short*)alloc((unsigned long long)G * PLANE_B);
  unsigned short* ql  = (unsigned short*)alloc((unsigned long long)G * PLANE_B);
  unsigned short* kh  = (unsigned short*)alloc((unsigned long long)G * PLANE_B);
  unsigned short* kl  = (unsigned short*)alloc((unsigned long long)G * PLANE_B);
  unsigned short* vT  = (unsigned short*)alloc((unsigned long long)G * PLANE_B);

  unsigned short* wqTh = (unsigned short*)slab;
  unsigned short* wqTl = (unsigned short*)(slab + WPLANE_B);
  unsigned short* wkTh = (unsigned short*)(slab + 2 * WPLANE_B);
  unsigned short* wkTl = (unsigned short*)(slab + 3 * WPLANE_B);

  unsigned short* iah = (unsigned short*)slab;
  unsigned short* ial = (unsigned short*)(slab + (unsigned long long)G * PLANE_B);
  float* Sg = (float*)slab;

  // M' = Wk^T Wq (hi+lo), tiny 1024^3
  tsplit_k<<<256, 256, 0, stream>>>(Wq, wqTh, wqTl);
  tsplit_k<<<256, 256, 0, stream>>>(Wk, wkTh, wkTl);
  split_h_k<<<512, 256, 0, stream>>>(Wv, wvh, WN / 4);
  gemm_bt<3, true><<<32, 256, 0, stream>>>(
      wkTh, wkTl, wqTh, wqTl, mph, mpl, DD, DD, 0, 0, 0, 8, 8);

  for (int b0 = 0; b0 < NB; b0 += G) {
    long long n4 = (long long)G * SD / 4;
    // z = x M'^T
    split_hl_k<<<2048, 256, 0, stream>>>(query + (long long)b0 * SD, iah, ial, n4);
    gemm_bt<3, true><<<G * 64, 256, 0, stream>>>(
        iah, ial, mph, mpl, qh, ql, DD, DD, SD, 0, SD, 16, 8);
    // key: exact hi/lo split (B operand of the score GEMM)
    split_hl_k<<<2048, 256, 0, stream>>>(key + (long long)b0 * SD, kh, kl, n4);
    // vT = Wv @ value^T
    split_h_k<<<2048, 256, 0, stream>>>(value + (long long)b0 * SD, iah, n4);
    gemm_bt<1, false><<<G * 64, 256, 0, stream>>>(
        wvh, nullptr, iah, nullptr, vT, nullptr, TT, DD, 0, SD, DT, 8, 16);
    // scores = z key^T (triangular), softmax, PV
    qk_bt<<<G * 136, 256, 0, stream>>>(qh, ql, kh, kl, Sg);
    softmax_kernel<<<G * SS, 256, 0, stream>>>(Sg);
    pv_bt<<<G * 128, 256, 0, stream>>>(
        (const unsigned short*)Sg, vT, Out + (long long)b0 * SD);
  }
}